// Round 2
// baseline (422.365 us; speedup 1.0000x reference)
//
#include <hip/hip_runtime.h>

// RotaryPositionEncoding3D: out[b,n,f,c] with f = bin*6 + axis*2 + dup,
// c = 0 (cos) / 1 (sin). Flat within-point index = bin*12 + axis*4 + dup*2 + c.
// One thread per output float4 (= one (point, bin, axis) triple):
// writes (cos, sin, cos, sin) — fully coalesced 16B stores.
// Store-BW-bound: 402.7 MB out / 6.3 TB/s ~= 65 us roofline.

__global__ __launch_bounds__(256) void rope3d_kernel(
    const float* __restrict__ xyz,       // [P, 3]
    const float* __restrict__ div_term,  // [32]
    float4* __restrict__ out,            // [P * 96] float4s
    int total_f4)
{
    __shared__ float s_div[32];
    if (threadIdx.x < 32) s_div[threadIdx.x] = div_term[threadIdx.x];
    __syncthreads();

    int g = blockIdx.x * blockDim.x + threadIdx.x;
    if (g >= total_f4) return;

    int p    = g / 96;          // point index
    int q    = g - p * 96;      // float4 index within point, [0,96)
    int bin  = q / 3;           // frequency bin, [0,32)
    int axis = q - bin * 3;     // 0=x, 1=y, 2=z

    float coord = xyz[p * 3 + axis];
    float dv    = s_div[bin];
    float ang   = coord * dv;   // |ang| <= 1 — fast sincos is plenty accurate

    float s, c;
    __sincosf(ang, &s, &c);

    out[g] = make_float4(c, s, c, s);
}

extern "C" void kernel_launch(void* const* d_in, const int* in_sizes, int n_in,
                              void* d_out, int out_size, void* d_ws, size_t ws_size,
                              hipStream_t stream) {
    const float* xyz      = (const float*)d_in[0];  // [B*N*3]
    const float* div_term = (const float*)d_in[1];  // [32]
    float*       out      = (float*)d_out;          // [B*N*192*2]

    int points   = in_sizes[0] / 3;       // B*N = 262144
    int total_f4 = points * 96;           // out_size/4

    const int block = 256;
    int grid = (total_f4 + block - 1) / block;
    rope3d_kernel<<<grid, block, 0, stream>>>(xyz, div_term, (float4*)out, total_f4);
}

// Round 3
// 405.164 us; speedup vs baseline: 1.0425x; 1.0425x over previous
//
#include <hip/hip_runtime.h>

// RotaryPositionEncoding3D: out[b,n,f,c] with f = bin*6 + axis*2 + dup,
// c = 0 (cos) / 1 (sin). Flat within-point index = bin*12 + axis*4 + dup*2 + c.
// One output float4 (= one (point, bin, axis) triple) = (cos, sin, cos, sin).
//
// Round-3 change: grid-stride loop, UNROLL float4s per thread. Stride between
// a thread's iterations is the whole grid, so each store instruction keeps
// lane-consecutive float4 addresses (perfect coalescing) while wave count
// drops 8x (per-wave setup overhead was ~60% of runtime at 1 store/thread).

#define UNROLL 8

__global__ __launch_bounds__(256) void rope3d_kernel(
    const float* __restrict__ xyz,       // [P, 3]
    const float* __restrict__ div_term,  // [32]
    float4* __restrict__ out,            // [P * 96] float4s
    int total_f4)
{
    __shared__ float s_div[32];
    if (threadIdx.x < 32) s_div[threadIdx.x] = div_term[threadIdx.x];
    __syncthreads();

    const int stride = blockDim.x * gridDim.x;   // grid-wide stride in float4s
    int g = blockIdx.x * blockDim.x + threadIdx.x;

#pragma unroll
    for (int k = 0; k < UNROLL; ++k) {
        if (g < total_f4) {
            unsigned int ug = (unsigned int)g;
            unsigned int p  = ug / 96u;          // point index (magic mul)
            unsigned int q  = ug - p * 96u;      // [0,96)
            unsigned int bin  = q / 3u;          // frequency bin [0,32)
            unsigned int axis = q - bin * 3u;    // 0=x 1=y 2=z

            float coord = xyz[p * 3u + axis];
            float ang   = coord * s_div[bin];    // |ang| <= 1

            float s, c;
            __sincosf(ang, &s, &c);
            out[g] = make_float4(c, s, c, s);
        }
        g += stride;
    }
}

extern "C" void kernel_launch(void* const* d_in, const int* in_sizes, int n_in,
                              void* d_out, int out_size, void* d_ws, size_t ws_size,
                              hipStream_t stream) {
    const float* xyz      = (const float*)d_in[0];  // [B*N*3]
    const float* div_term = (const float*)d_in[1];  // [32]
    float*       out      = (float*)d_out;          // [B*N*192*2]

    int points   = in_sizes[0] / 3;       // B*N
    int total_f4 = points * 96;           // out_size / 4

    const int block = 256;
    int grid = (total_f4 + block * UNROLL - 1) / (block * UNROLL);
    rope3d_kernel<<<grid, block, 0, stream>>>(xyz, div_term, (float4*)out, total_f4);
}